// Round 9
// baseline (313.761 us; speedup 1.0000x reference)
//
#include <hip/hip_runtime.h>

#define KNN 16
#define FSEM 32
#define LPG 4                 // 4 lanes cooperate per gaussian
#define NXCD 8

__device__ __forceinline__ float sigmoidf_(float x) { return 1.0f / (1.0f + __expf(-x)); }

// q / clip(|q|,1e-12) -> row-major 3x3
__device__ __forceinline__ void quat_to_R(float qw, float qx, float qy, float qz, float* R) {
    float d = qw * qw + qx * qx + qy * qy + qz * qz;
    float inv = rsqrtf(fmaxf(d, 1e-24f));
    float w = qw * inv, x = qx * inv, y = qy * inv, z = qz * inv;
    R[0] = 1.f - 2.f * (y * y + z * z); R[1] = 2.f * (x * y - w * z); R[2] = 2.f * (x * z + w * y);
    R[3] = 2.f * (x * y + w * z); R[4] = 1.f - 2.f * (x * x + z * z); R[5] = 2.f * (y * z - w * x);
    R[6] = 2.f * (x * z - w * y); R[7] = 2.f * (y * z + w * x); R[8] = 1.f - 2.f * (x * x + y * y);
}

__device__ __forceinline__ void elem_outputs(int n, int N,
                                             const float* __restrict__ gs_scal,
                                             const float* __restrict__ gs_opa,
                                             const float* __restrict__ feat_dc,
                                             const float* __restrict__ feat_rest,
                                             float* __restrict__ out)
{
    const size_t Ns = (size_t)N, ns = (size_t)n;
    float* os = out + 12 * Ns + 3 * ns;
    os[0] = 0.1f * sigmoidf_(gs_scal[3 * ns + 0]);
    os[1] = 0.1f * sigmoidf_(gs_scal[3 * ns + 1]);
    os[2] = 0.1f * sigmoidf_(gs_scal[3 * ns + 2]);

    out[15 * Ns + ns] = sigmoidf_(gs_opa[ns]);

    float* osph = out + 16 * Ns + 12 * ns;   // 16B-aligned
    float4 v0 = make_float4(feat_dc[3 * ns + 0], feat_dc[3 * ns + 1], feat_dc[3 * ns + 2],
                            feat_rest[9 * ns + 0]);
    float4 v1 = make_float4(feat_rest[9 * ns + 1], feat_rest[9 * ns + 2],
                            feat_rest[9 * ns + 3], feat_rest[9 * ns + 4]);
    float4 v2 = make_float4(feat_rest[9 * ns + 5], feat_rest[9 * ns + 6],
                            feat_rest[9 * ns + 7], feat_rest[9 * ns + 8]);
    reinterpret_cast<float4*>(osph)[0] = v0;
    reinterpret_cast<float4*>(osph)[1] = v1;
    reinterpret_cast<float4*>(osph)[2] = v2;
}

// ---- pack (quats PRE-NORMALIZED) + exact-key histogram (key = rt*M + a).
// cnt pre-zeroed by memset. ----
__global__ void __launch_bounds__(256)
k_pack_hist(const float* __restrict__ node_xyz, const float* __restrict__ node_quat,
            const float* __restrict__ node_sigma,
            const int* __restrict__ attach, const int* __restrict__ rtime,
            float* __restrict__ packed, int* __restrict__ cnt,
            int TM, int M, int N)
{
    const int p = blockIdx.x * blockDim.x + threadIdx.x;
    if (p < TM) {
        const int node = p - (p / M) * M;          // p % M
        const float* x = node_xyz + 3 * (size_t)p;
        float4 q = reinterpret_cast<const float4*>(node_quat)[p];
        const float inv = rsqrtf(fmaxf(q.x * q.x + q.y * q.y + q.z * q.z + q.w * q.w, 1e-24f));
        q.x *= inv; q.y *= inv; q.z *= inv; q.w *= inv;
        float4 a = make_float4(x[0], x[1], x[2], node_sigma[node]);
        float4* dst = reinterpret_cast<float4*>(packed + 8 * (size_t)p);
        dst[0] = a;
        dst[1] = q;
    }
    if (cnt && p < N) {
        atomicAdd(&cnt[rtime[p] * M + attach[p]], 1);
    }
}

// ---- fused two-level scan: per-chunk scan, then the LAST block to finish
// (device-scope ticket, no spinning — R7 proved grid.sync costs ~145us) scans
// the chunk totals. done must be pre-zeroed. ----
__global__ void __launch_bounds__(256)
k_scan(int* __restrict__ cnt, int* __restrict__ blk, int* __restrict__ done,
       int B, int nchunk)
{
    __shared__ int sh[256];
    __shared__ int ticket_s;
    const int i = blockIdx.x * 256 + threadIdx.x;
    int v = (i < B) ? cnt[i] : 0;
    sh[threadIdx.x] = v;
    __syncthreads();
    int acc = v;
#pragma unroll
    for (int off = 1; off < 256; off <<= 1) {
        int u = (threadIdx.x >= off) ? sh[threadIdx.x - off] : 0;
        __syncthreads();
        acc += u;
        sh[threadIdx.x] = acc;
        __syncthreads();
    }
    if (i < B) cnt[i] = acc - v;                 // exclusive within chunk
    if (threadIdx.x == 255) blk[blockIdx.x] = acc;   // chunk total

    // last-block-finishes: fence makes this block's blk write visible, then
    // the block drawing the final ticket sees ALL blk writes (each predecessor
    // fenced before its atomic).
    __threadfence();
    __syncthreads();
    if (threadIdx.x == 0) ticket_s = atomicAdd(done, 1);
    __syncthreads();
    if (ticket_s != nchunk - 1) return;

    volatile int* vblk = blk;                    // bypass L1 (cross-XCD writes)
    __shared__ int carry_s;
    if (threadIdx.x == 0) carry_s = 0;
    __syncthreads();
    for (int base = 0; base < nchunk; base += 256) {
        const int idx = base + threadIdx.x;
        int t = (idx < nchunk) ? vblk[idx] : 0;
        sh[threadIdx.x] = t;
        __syncthreads();
        int a2 = t;
#pragma unroll
        for (int off = 1; off < 256; off <<= 1) {
            int u = (threadIdx.x >= off) ? sh[threadIdx.x - off] : 0;
            __syncthreads();
            a2 += u;
            sh[threadIdx.x] = a2;
            __syncthreads();
        }
        const int carry = carry_s;
        if (idx < nchunk) blk[idx] = a2 - t + carry;
        __syncthreads();
        if (threadIdx.x == 255) carry_s = carry + a2;
        __syncthreads();
    }
}

// ---- scatter (rank-free: scanned cnt doubles as live cursor) + elem fused.
// metaA[2p]   = {n, a, rt, 0} (int bits)   metaA[2p+1] = {gx,gy,gz,0}
// rotA[p]     = gs_rot[n]  (coalesced stream for main's fr epilogue) ----
__global__ void __launch_bounds__(256)
k_scatter_elem(const int* __restrict__ attach, const int* __restrict__ rtime,
               const float* __restrict__ gs_xyz,
               const float* __restrict__ gs_rot,
               int* __restrict__ cnt, const int* __restrict__ blk,
               float4* __restrict__ metaA, float4* __restrict__ rotA,
               const float* __restrict__ gs_scal,
               const float* __restrict__ gs_opa,
               const float* __restrict__ feat_dc,
               const float* __restrict__ feat_rest,
               float* __restrict__ out,
               int N, int M)
{
    const int n = blockIdx.x * blockDim.x + threadIdx.x;
    if (n >= N) return;
    const int a = attach[n], rt = rtime[n];
    const int key = rt * M + a;
    const int pos = blk[key >> 8] + atomicAdd(&cnt[key], 1);

    metaA[2 * (size_t)pos]     = make_float4(__int_as_float(n), __int_as_float(a),
                                             __int_as_float(rt), 0.f);
    metaA[2 * (size_t)pos + 1] = make_float4(gs_xyz[3 * (size_t)n + 0],
                                             gs_xyz[3 * (size_t)n + 1],
                                             gs_xyz[3 * (size_t)n + 2], 0.f);
    rotA[pos] = reinterpret_cast<const float4*>(gs_rot)[n];

    elem_outputs(n, N, gs_scal, gs_opa, feat_dc, feat_rest, out);
}

// ---- plain elementwise kernel (fallback tiers only) ----
__global__ void __launch_bounds__(256)
k_elem(const float* __restrict__ gs_scal,
       const float* __restrict__ gs_opa,
       const float* __restrict__ feat_dc,
       const float* __restrict__ feat_rest,
       float* __restrict__ out, int N)
{
    const int n = blockIdx.x * blockDim.x + threadIdx.x;
    if (n >= N) return;
    elem_outputs(n, N, gs_scal, gs_opa, feat_dc, feat_rest, out);
}

// ---- main skinning kernel: mu, fr (fused), sem FUSED INTO GATHER LOOP ----
// sem loads depend only on js (shfl) — fusing them per-k lets the scheduler
// hoist them under the packed-gather->exp chain: ~12 independent loads/iter
// in flight instead of 4 (R8: VALUBusy 24%, 76% stall on L2 latency).
template<bool PACKED, bool SORTED>
__global__ void __launch_bounds__(256)
dynscf_kernel(const float* __restrict__ gs_xyz,
              const float* __restrict__ gs_rot,
              const float* __restrict__ node_xyz,
              const float* __restrict__ node_quat,
              const float* __restrict__ packed,
              const float* __restrict__ node_sigma,
              const float* __restrict__ node_sem,
              const int* __restrict__ attach_ind,
              const int* __restrict__ ref_time,
              const int* __restrict__ topo_knn,
              const int* __restrict__ t_ptr,
              const float4* __restrict__ metaA,
              const float4* __restrict__ rotA,
              float* __restrict__ out,
              int N, int M)
{
    int bid = blockIdx.x;
    if (SORTED) {
        // m204 bijective chunked XCD swizzle: contiguous sorted range per XCD.
        const int nwg = gridDim.x;
        const int q = nwg / NXCD, r = nwg % NXCD;
        const int xcd = bid % NXCD, idx = bid / NXCD;
        bid = (xcd < r ? xcd * (q + 1) : r * (q + 1) + (xcd - r) * q) + idx;
    }
    const int tid = bid * blockDim.x + threadIdx.x;
    const int g   = tid >> 2;            // sorted-order group index
    const int sub = tid & (LPG - 1);
    if (g >= N) return;

    const int t = t_ptr[0];

    int n, a, rt;
    float gx, gy, gz;
    if (SORTED) {
        const float4 m0 = metaA[2 * (size_t)g];
        const float4 m1 = metaA[2 * (size_t)g + 1];
        n  = __float_as_int(m0.x);
        a  = __float_as_int(m0.y);
        rt = __float_as_int(m0.z);
        gx = m1.x; gy = m1.y; gz = m1.z;
    } else {
        n  = g;
        a  = attach_ind[n];
        rt = ref_time[n];
        gx = gs_xyz[3 * (size_t)n + 0];
        gy = gs_xyz[3 * (size_t)n + 1];
        gz = gs_xyz[3 * (size_t)n + 2];
    }

    const size_t base_rt = (size_t)rt * (size_t)M;
    const size_t base_t  = (size_t)t  * (size_t)M;

    const int4 kv = reinterpret_cast<const int4*>(topo_knn)[(size_t)a * (KNN / 4) + sub];
    const int js[4] = { kv.x, kv.y, kv.z, kv.w };

    // --- attach node @ ref time ---
    float apx, apy, apz, aqw, aqx, aqy, aqz;
    if (PACKED) {
        const float4* pk = reinterpret_cast<const float4*>(packed + (base_rt + (size_t)a) * 8);
        float4 xz = pk[0], qv = pk[1];
        apx = xz.x; apy = xz.y; apz = xz.z;
        aqw = qv.x; aqx = qv.y; aqy = qv.z; aqz = qv.w;
    } else {
        const float4 qv = *reinterpret_cast<const float4*>(node_quat + (base_rt + (size_t)a) * 4);
        const float* pa = node_xyz + (base_rt + (size_t)a) * 3;
        apx = pa[0]; apy = pa[1]; apz = pa[2];
        aqw = qv.x; aqx = qv.y; aqy = qv.z; aqz = qv.w;
    }
    float xw0, xw1, xw2;
    {
        float Rf[9];
        quat_to_R(aqw, aqx, aqy, aqz, Rf);
        xw0 = Rf[0] * gx + Rf[1] * gy + Rf[2] * gz + apx;
        xw1 = Rf[3] * gx + Rf[4] * gy + Rf[5] * gz + apy;
        xw2 = Rf[6] * gx + Rf[7] * gy + Rf[8] * gz + apz;
    }

    float wsum = 0.f, mu0 = 0.f, mu1 = 0.f, mu2 = 0.f;
    float qb0 = 0.f, qb1 = 0.f, qb2 = 0.f, qb3 = 0.f;
    float sm0 = 0.f, sm1 = 0.f, sm2 = 0.f, sm3 = 0.f;
    float sm4 = 0.f, sm5 = 0.f, sm6 = 0.f, sm7 = 0.f;
    const float4* sem4 = reinterpret_cast<const float4*>(node_sem);

#pragma unroll
    for (int k = 0; k < KNN / LPG; k++) {
        const int j = js[k];

        float prx, pry, prz, rw, rx, ry, rz;
        float plx, ply, plz, lw, lx, ly, lz;
        float sg;
        if (PACKED) {
            const float4* pkr = reinterpret_cast<const float4*>(packed + (base_rt + (size_t)j) * 8);
            float4 xr = pkr[0], qr = pkr[1];
            prx = xr.x; pry = xr.y; prz = xr.z; sg = xr.w;
            rw = qr.x; rx = qr.y; ry = qr.z; rz = qr.w;
            const float4* pkl = reinterpret_cast<const float4*>(packed + (base_t + (size_t)j) * 8);
            float4 xl = pkl[0], ql = pkl[1];
            plx = xl.x; ply = xl.y; plz = xl.z;
            lw = ql.x; lx = ql.y; ly = ql.z; lz = ql.w;
        } else {
            const float* pr = node_xyz + (base_rt + (size_t)j) * 3;
            prx = pr[0]; pry = pr[1]; prz = pr[2];
            const float4 qr = *reinterpret_cast<const float4*>(node_quat + (base_rt + (size_t)j) * 4);
            rw = qr.x; rx = qr.y; ry = qr.z; rz = qr.w;
            const float* pl = node_xyz + (base_t + (size_t)j) * 3;
            plx = pl[0]; ply = pl[1]; plz = pl[2];
            const float4 ql = *reinterpret_cast<const float4*>(node_quat + (base_t + (size_t)j) * 4);
            lw = ql.x; lx = ql.y; ly = ql.z; lz = ql.w;
            sg = node_sigma[j];
        }

        const float dx = xw0 - prx;
        const float dy = xw1 - pry;
        const float dz = xw2 - prz;
        const float dsq = dx * dx + dy * dy + dz * dz;

        const float w = __expf(-dsq / (2.f * sg * sg + 1e-8f));

        if (!PACKED) {
            // packed path stores normalized quats; raw path normalizes here
            float inv = rsqrtf(fmaxf(rw * rw + rx * rx + ry * ry + rz * rz, 1e-24f));
            rw *= inv; rx *= inv; ry *= inv; rz *= inv;
            inv = rsqrtf(fmaxf(lw * lw + lx * lx + ly * ly + lz * lz, 1e-24f));
            lw *= inv; lx *= inv; ly *= inv; lz *= inv;
        }
        // q_rel = q_live * conj(q_ref)
        const float qw =  lw * rw + lx * rx + ly * ry + lz * rz;
        const float qx = -lw * rx + lx * rw - ly * rz + lz * ry;
        const float qy = -lw * ry + lx * rz + ly * rw - lz * rx;
        const float qz = -lw * rz - lx * ry + ly * rx + lz * rw;

        float Rr[9];
        quat_to_R(qw, qx, qy, qz, Rr);

        const float m0 = Rr[0] * dx + Rr[1] * dy + Rr[2] * dz + plx;
        const float m1 = Rr[3] * dx + Rr[4] * dy + Rr[5] * dz + ply;
        const float m2 = Rr[6] * dx + Rr[7] * dy + Rr[8] * dz + plz;

        wsum += w;
        mu0 += w * m0; mu1 += w * m1; mu2 += w * m2;
        qb0 += w * qw; qb1 += w * qx; qb2 += w * qy; qb3 += w * qz;

        // --- sem fused: process the 4 neighbors at slot k (one per owner lane).
        // jk depends only on js (known at loop top) -> scheduler can hoist the
        // sem loads under the packed-gather/exp dependency chain.
#pragma unroll
        for (int src = 0; src < LPG; src++) {
            const int   jk  = __shfl(j, src, LPG);
            const float wkk = __shfl(w, src, LPG);
            const float4 v0 = sem4[(size_t)jk * (FSEM / 4) + sub * 2 + 0];
            const float4 v1 = sem4[(size_t)jk * (FSEM / 4) + sub * 2 + 1];
            sm0 += wkk * v0.x; sm1 += wkk * v0.y; sm2 += wkk * v0.z; sm3 += wkk * v0.w;
            sm4 += wkk * v1.x; sm5 += wkk * v1.y; sm6 += wkk * v1.z; sm7 += wkk * v1.w;
        }
    }

#pragma unroll
    for (int m = 1; m < LPG; m <<= 1) {
        wsum += __shfl_xor(wsum, m);
        mu0  += __shfl_xor(mu0, m);  mu1 += __shfl_xor(mu1, m);  mu2 += __shfl_xor(mu2, m);
        qb0  += __shfl_xor(qb0, m);  qb1 += __shfl_xor(qb1, m);
        qb2  += __shfl_xor(qb2, m);  qb3 += __shfl_xor(qb3, m);
    }

    const float invw = 1.f / (wsum + 1e-8f);
    const size_t Ns = (size_t)N, ns = (size_t)n;

    if (sub == 0) {
        out[3 * ns + 0] = mu0 * invw;
        out[3 * ns + 1] = mu1 * invw;
        out[3 * ns + 2] = mu2 * invw;
    } else if (sub == 1) {
        // fr_live = q2R(qb*invw) @ (Rref @ q2R(gs_rot)); invw BEFORE q2R (fp32
        // subnormal guard). Rref recomputed from the live attach quat.
        float4 qg;
        if (SORTED) qg = rotA[g];
        else        qg = *reinterpret_cast<const float4*>(gs_rot + 4 * ns);
        float Rref[9];
        quat_to_R(aqw, aqx, aqy, aqz, Rref);
        float Rg[9];
        quat_to_R(qg.x, qg.y, qg.z, qg.w, Rg);
        float Rw[9];
#pragma unroll
        for (int i = 0; i < 3; i++)
#pragma unroll
            for (int j = 0; j < 3; j++)
                Rw[3 * i + j] = Rref[3 * i] * Rg[j] + Rref[3 * i + 1] * Rg[3 + j] + Rref[3 * i + 2] * Rg[6 + j];
        float Rb[9];
        quat_to_R(qb0 * invw, qb1 * invw, qb2 * invw, qb3 * invw, Rb);
        float* ofr = out + 3 * Ns + 9 * ns;
#pragma unroll
        for (int i = 0; i < 3; i++)
#pragma unroll
            for (int j = 0; j < 3; j++)
                ofr[3 * i + j] = Rb[3 * i] * Rw[j] + Rb[3 * i + 1] * Rw[3 + j] + Rb[3 * i + 2] * Rw[6 + j];
    }

    float4* osem = reinterpret_cast<float4*>(out + 28 * Ns + FSEM * ns);
    osem[sub * 2 + 0] = make_float4(sm0 * invw, sm1 * invw, sm2 * invw, sm3 * invw);
    osem[sub * 2 + 1] = make_float4(sm4 * invw, sm5 * invw, sm6 * invw, sm7 * invw);
}

extern "C" void kernel_launch(void* const* d_in, const int* in_sizes, int n_in,
                              void* d_out, int out_size, void* d_ws, size_t ws_size,
                              hipStream_t stream)
{
    const float* gs_xyz     = (const float*)d_in[0];
    const float* gs_rot     = (const float*)d_in[1];
    const float* gs_scal    = (const float*)d_in[2];
    const float* gs_opa     = (const float*)d_in[3];
    const float* feat_dc    = (const float*)d_in[4];
    const float* feat_rest  = (const float*)d_in[5];
    const float* node_xyz   = (const float*)d_in[6];
    const float* node_quat  = (const float*)d_in[7];
    const float* node_sigma = (const float*)d_in[8];
    const float* node_sem   = (const float*)d_in[9];
    const int* attach_ind   = (const int*)d_in[10];
    const int* ref_time     = (const int*)d_in[11];
    const int* topo_knn     = (const int*)d_in[12];
    const int* t_ptr        = (const int*)d_in[13];

    const int N = in_sizes[0] / 3;
    const int M = in_sizes[8];                 // node_sigma is (M,1)
    const int TM = in_sizes[6] / 3;            // T*M
    const int B  = TM;                         // exact sort buckets: key = rt*M + a
    const int nchunk = (B + 255) / 256;

    float* out = (float*)d_out;

    const int block = 256;
    const int gridN = (N + block - 1) / block;
    const long long threads = (long long)N * LPG;
    const int gridM = (int)((threads + block - 1) / block);
    const int gridPH = (((TM > N ? TM : N)) + block - 1) / block;

    // workspace layout (floats): packed | metaA | rotA | cnt | blk | done
    const size_t f_packed = (size_t)TM * 8;
    const size_t f_meta   = (size_t)N * 8;
    const size_t f_rot    = (size_t)N * 4;
    const size_t i_cnt    = (size_t)B;
    const size_t i_blk    = 4096;
    const size_t i_done   = 64;
    const size_t need_sort   = (f_packed + f_meta + f_rot + i_cnt + i_blk + i_done) * sizeof(float);
    const size_t need_packed = f_packed * sizeof(float);

    if (ws_size >= need_sort && nchunk <= 4096) {
        float*  packed = (float*)d_ws;
        float4* metaA  = (float4*)(packed + f_packed);
        float4* rotA   = (float4*)(packed + f_packed + f_meta);
        int*    cnt    = (int*)(packed + f_packed + f_meta + f_rot);
        int*    blk    = cnt + i_cnt;
        int*    done   = blk + i_blk;

        // one memset covers cnt + blk + done (contiguous)
        hipMemsetAsync(cnt, 0, (i_cnt + i_blk + i_done) * sizeof(int), stream);
        hipLaunchKernelGGL(k_pack_hist, dim3(gridPH), dim3(block), 0, stream,
                           node_xyz, node_quat, node_sigma, attach_ind, ref_time,
                           packed, cnt, TM, M, N);
        hipLaunchKernelGGL(k_scan, dim3(nchunk), dim3(block), 0, stream,
                           cnt, blk, done, B, nchunk);
        hipLaunchKernelGGL(k_scatter_elem, dim3(gridN), dim3(block), 0, stream,
                           attach_ind, ref_time, gs_xyz, gs_rot, cnt, blk,
                           metaA, rotA, gs_scal, gs_opa, feat_dc, feat_rest,
                           out, N, M);
        hipLaunchKernelGGL((dynscf_kernel<true, true>), dim3(gridM), dim3(block), 0, stream,
                           gs_xyz, gs_rot, node_xyz, node_quat, packed, node_sigma, node_sem,
                           attach_ind, ref_time, topo_knn, t_ptr, metaA, rotA, out, N, M);
    } else if (ws_size >= need_packed) {
        float* packed = (float*)d_ws;
        hipLaunchKernelGGL(k_pack_hist, dim3(gridPH), dim3(block), 0, stream,
                           node_xyz, node_quat, node_sigma, attach_ind, ref_time,
                           packed, (int*)nullptr, TM, M, 0);
        hipLaunchKernelGGL((dynscf_kernel<true, false>), dim3(gridM), dim3(block), 0, stream,
                           gs_xyz, gs_rot, node_xyz, node_quat, packed, node_sigma, node_sem,
                           attach_ind, ref_time, topo_knn, t_ptr,
                           (const float4*)nullptr, (const float4*)nullptr, out, N, M);
        hipLaunchKernelGGL(k_elem, dim3(gridN), dim3(block), 0, stream,
                           gs_scal, gs_opa, feat_dc, feat_rest, out, N);
    } else {
        hipLaunchKernelGGL((dynscf_kernel<false, false>), dim3(gridM), dim3(block), 0, stream,
                           gs_xyz, gs_rot, node_xyz, node_quat, (const float*)nullptr,
                           node_sigma, node_sem,
                           attach_ind, ref_time, topo_knn, t_ptr,
                           (const float4*)nullptr, (const float4*)nullptr, out, N, M);
        hipLaunchKernelGGL(k_elem, dim3(gridN), dim3(block), 0, stream,
                           gs_scal, gs_opa, feat_dc, feat_rest, out, N);
    }
}

// Round 10
// 209.259 us; speedup vs baseline: 1.4994x; 1.4994x over previous
//
#include <hip/hip_runtime.h>

#define KNN 16
#define FSEM 32
#define LPG 4                 // 4 lanes cooperate per gaussian
#define NXCD 8
#define CHUNK 1024            // scan1 buckets per block (B=400K -> 391 chunks)
#define MAXCHUNK 512          // scatter's in-LDS prefix capacity (>= nchunk)

__device__ __forceinline__ float sigmoidf_(float x) { return 1.0f / (1.0f + __expf(-x)); }

// q / clip(|q|,1e-12) -> row-major 3x3
__device__ __forceinline__ void quat_to_R(float qw, float qx, float qy, float qz, float* R) {
    float d = qw * qw + qx * qx + qy * qy + qz * qz;
    float inv = rsqrtf(fmaxf(d, 1e-24f));
    float w = qw * inv, x = qx * inv, y = qy * inv, z = qz * inv;
    R[0] = 1.f - 2.f * (y * y + z * z); R[1] = 2.f * (x * y - w * z); R[2] = 2.f * (x * z + w * y);
    R[3] = 2.f * (x * y + w * z); R[4] = 1.f - 2.f * (x * x + z * z); R[5] = 2.f * (y * z - w * x);
    R[6] = 2.f * (x * z - w * y); R[7] = 2.f * (y * z + w * x); R[8] = 1.f - 2.f * (x * x + y * y);
}

__device__ __forceinline__ void elem_outputs(int n, int N,
                                             const float* __restrict__ gs_scal,
                                             const float* __restrict__ gs_opa,
                                             const float* __restrict__ feat_dc,
                                             const float* __restrict__ feat_rest,
                                             float* __restrict__ out)
{
    const size_t Ns = (size_t)N, ns = (size_t)n;
    float* os = out + 12 * Ns + 3 * ns;
    os[0] = 0.1f * sigmoidf_(gs_scal[3 * ns + 0]);
    os[1] = 0.1f * sigmoidf_(gs_scal[3 * ns + 1]);
    os[2] = 0.1f * sigmoidf_(gs_scal[3 * ns + 2]);

    out[15 * Ns + ns] = sigmoidf_(gs_opa[ns]);

    float* osph = out + 16 * Ns + 12 * ns;   // 16B-aligned
    float4 v0 = make_float4(feat_dc[3 * ns + 0], feat_dc[3 * ns + 1], feat_dc[3 * ns + 2],
                            feat_rest[9 * ns + 0]);
    float4 v1 = make_float4(feat_rest[9 * ns + 1], feat_rest[9 * ns + 2],
                            feat_rest[9 * ns + 3], feat_rest[9 * ns + 4]);
    float4 v2 = make_float4(feat_rest[9 * ns + 5], feat_rest[9 * ns + 6],
                            feat_rest[9 * ns + 7], feat_rest[9 * ns + 8]);
    reinterpret_cast<float4*>(osph)[0] = v0;
    reinterpret_cast<float4*>(osph)[1] = v1;
    reinterpret_cast<float4*>(osph)[2] = v2;
}

// ---- pack (quats PRE-NORMALIZED) + exact-key histogram (key = rt*M + a).
// cnt pre-zeroed by memset. ----
__global__ void __launch_bounds__(256)
k_pack_hist(const float* __restrict__ node_xyz, const float* __restrict__ node_quat,
            const float* __restrict__ node_sigma,
            const int* __restrict__ attach, const int* __restrict__ rtime,
            float* __restrict__ packed, int* __restrict__ cnt,
            int TM, int M, int N)
{
    const int p = blockIdx.x * blockDim.x + threadIdx.x;
    if (p < TM) {
        const int node = p - (p / M) * M;          // p % M
        const float* x = node_xyz + 3 * (size_t)p;
        float4 q = reinterpret_cast<const float4*>(node_quat)[p];
        const float inv = rsqrtf(fmaxf(q.x * q.x + q.y * q.y + q.z * q.z + q.w * q.w, 1e-24f));
        q.x *= inv; q.y *= inv; q.z *= inv; q.w *= inv;
        float4 a = make_float4(x[0], x[1], x[2], node_sigma[node]);
        float4* dst = reinterpret_cast<float4*>(packed + 8 * (size_t)p);
        dst[0] = a;
        dst[1] = q;
    }
    if (cnt && p < N) {
        atomicAdd(&cnt[rtime[p] * M + attach[p]], 1);
    }
}

// ---- scan1: per-block exclusive scan over CHUNK=1024 buckets (int4 per
// thread), chunk total -> blk[c]. No device fences (R9: __threadfence per
// block = 110us; cross-block coordination stays at dispatch boundaries). ----
__global__ void __launch_bounds__(256)
k_scan1(int* __restrict__ cnt, int* __restrict__ blk, int B)
{
    __shared__ int sh[256];
    const int base = blockIdx.x * CHUNK + threadIdx.x * 4;
    int4 v = make_int4(0, 0, 0, 0);
    if (base + 3 < B) v = *reinterpret_cast<const int4*>(&cnt[base]);   // B%4==0
    const int s = v.x + v.y + v.z + v.w;

    sh[threadIdx.x] = s;
    __syncthreads();
    int acc = s;
#pragma unroll
    for (int off = 1; off < 256; off <<= 1) {
        int u = (threadIdx.x >= off) ? sh[threadIdx.x - off] : 0;
        __syncthreads();
        acc += u;
        sh[threadIdx.x] = acc;
        __syncthreads();
    }
    const int excl = acc - s;                    // exclusive across threads

    if (base + 3 < B) {
        int4 w;
        w.x = excl;
        w.y = excl + v.x;
        w.z = excl + v.x + v.y;
        w.w = excl + v.x + v.y + v.z;
        *reinterpret_cast<int4*>(&cnt[base]) = w;    // exclusive within chunk
    }
    if (threadIdx.x == 255) blk[blockIdx.x] = acc;   // chunk total
}

// ---- scatter + elem fused; computes the chunk-total prefix IN-BLOCK
// (391 totals, pair-sum + 256-scan in LDS; redundant per block but fully
// parallel -> replaces the scan2 dispatch with ~1us/block of LDS work).
// metaA[2p]   = {n, a, rt, 0} (int bits)   metaA[2p+1] = {gx,gy,gz,0}
// rotA[p]     = gs_rot[n]  (coalesced stream for main's fr epilogue) ----
__global__ void __launch_bounds__(256)
k_scatter_elem(const int* __restrict__ attach, const int* __restrict__ rtime,
               const float* __restrict__ gs_xyz,
               const float* __restrict__ gs_rot,
               int* __restrict__ cnt, const int* __restrict__ blk,
               float4* __restrict__ metaA, float4* __restrict__ rotA,
               const float* __restrict__ gs_scal,
               const float* __restrict__ gs_opa,
               const float* __restrict__ feat_dc,
               const float* __restrict__ feat_rest,
               float* __restrict__ out,
               int N, int M, int nchunk)
{
    __shared__ int raw[MAXCHUNK];    // raw chunk totals
    __shared__ int ps[256];          // pair-sum scan workspace

    // load totals (<=512) and build pair sums
    {
        const int i0 = threadIdx.x, i1 = threadIdx.x + 256;
        raw[i0] = (i0 < nchunk) ? blk[i0] : 0;
        raw[i1] = (i1 < nchunk) ? blk[i1] : 0;
    }
    __syncthreads();
    {
        const int pairsum = raw[2 * threadIdx.x] + raw[2 * threadIdx.x + 1];
        ps[threadIdx.x] = pairsum;
        __syncthreads();
        int acc = pairsum;
#pragma unroll
        for (int off = 1; off < 256; off <<= 1) {
            int u = (threadIdx.x >= off) ? ps[threadIdx.x - off] : 0;
            __syncthreads();
            acc += u;
            ps[threadIdx.x] = acc;
            __syncthreads();
        }
        // make ps exclusive: ps[t] = sum of pairs [0,t)
        const int excl = acc - pairsum;
        __syncthreads();
        ps[threadIdx.x] = excl;
    }
    __syncthreads();

    const int n = blockIdx.x * blockDim.x + threadIdx.x;
    if (n >= N) return;
    const int a = attach[n], rt = rtime[n];
    const int key = rt * M + a;
    const int c = key / CHUNK;       // CHUNK=1024: compiler -> shift
    const int cpref = ps[c >> 1] + ((c & 1) ? raw[c & ~1] : 0);
    const int pos = cpref + atomicAdd(&cnt[key], 1);

    metaA[2 * (size_t)pos]     = make_float4(__int_as_float(n), __int_as_float(a),
                                             __int_as_float(rt), 0.f);
    metaA[2 * (size_t)pos + 1] = make_float4(gs_xyz[3 * (size_t)n + 0],
                                             gs_xyz[3 * (size_t)n + 1],
                                             gs_xyz[3 * (size_t)n + 2], 0.f);
    rotA[pos] = reinterpret_cast<const float4*>(gs_rot)[n];

    elem_outputs(n, N, gs_scal, gs_opa, feat_dc, feat_rest, out);
}

// ---- plain elementwise kernel (fallback tiers only) ----
__global__ void __launch_bounds__(256)
k_elem(const float* __restrict__ gs_scal,
       const float* __restrict__ gs_opa,
       const float* __restrict__ feat_dc,
       const float* __restrict__ feat_rest,
       float* __restrict__ out, int N)
{
    const int n = blockIdx.x * blockDim.x + threadIdx.x;
    if (n >= N) return;
    elem_outputs(n, N, gs_scal, gs_opa, feat_dc, feat_rest, out);
}

// ---- main skinning kernel: mu, fr (fused), sem (split second pass — R9
// proved fusing sem into the gather loop is neutral: compiler already
// overlaps those loads). R8-proven 67us configuration. ----
template<bool PACKED, bool SORTED>
__global__ void __launch_bounds__(256)
dynscf_kernel(const float* __restrict__ gs_xyz,
              const float* __restrict__ gs_rot,
              const float* __restrict__ node_xyz,
              const float* __restrict__ node_quat,
              const float* __restrict__ packed,
              const float* __restrict__ node_sigma,
              const float* __restrict__ node_sem,
              const int* __restrict__ attach_ind,
              const int* __restrict__ ref_time,
              const int* __restrict__ topo_knn,
              const int* __restrict__ t_ptr,
              const float4* __restrict__ metaA,
              const float4* __restrict__ rotA,
              float* __restrict__ out,
              int N, int M)
{
    int bid = blockIdx.x;
    if (SORTED) {
        // m204 bijective chunked XCD swizzle: contiguous sorted range per XCD.
        const int nwg = gridDim.x;
        const int q = nwg / NXCD, r = nwg % NXCD;
        const int xcd = bid % NXCD, idx = bid / NXCD;
        bid = (xcd < r ? xcd * (q + 1) : r * (q + 1) + (xcd - r) * q) + idx;
    }
    const int tid = bid * blockDim.x + threadIdx.x;
    const int g   = tid >> 2;            // sorted-order group index
    const int sub = tid & (LPG - 1);
    if (g >= N) return;

    const int t = t_ptr[0];

    int n, a, rt;
    float gx, gy, gz;
    if (SORTED) {
        const float4 m0 = metaA[2 * (size_t)g];
        const float4 m1 = metaA[2 * (size_t)g + 1];
        n  = __float_as_int(m0.x);
        a  = __float_as_int(m0.y);
        rt = __float_as_int(m0.z);
        gx = m1.x; gy = m1.y; gz = m1.z;
    } else {
        n  = g;
        a  = attach_ind[n];
        rt = ref_time[n];
        gx = gs_xyz[3 * (size_t)n + 0];
        gy = gs_xyz[3 * (size_t)n + 1];
        gz = gs_xyz[3 * (size_t)n + 2];
    }

    const size_t base_rt = (size_t)rt * (size_t)M;
    const size_t base_t  = (size_t)t  * (size_t)M;

    const int4 kv = reinterpret_cast<const int4*>(topo_knn)[(size_t)a * (KNN / 4) + sub];
    const int js[4] = { kv.x, kv.y, kv.z, kv.w };

    // --- attach node @ ref time ---
    float apx, apy, apz, aqw, aqx, aqy, aqz;
    if (PACKED) {
        const float4* pk = reinterpret_cast<const float4*>(packed + (base_rt + (size_t)a) * 8);
        float4 xz = pk[0], qv = pk[1];
        apx = xz.x; apy = xz.y; apz = xz.z;
        aqw = qv.x; aqx = qv.y; aqy = qv.z; aqz = qv.w;
    } else {
        const float4 qv = *reinterpret_cast<const float4*>(node_quat + (base_rt + (size_t)a) * 4);
        const float* pa = node_xyz + (base_rt + (size_t)a) * 3;
        apx = pa[0]; apy = pa[1]; apz = pa[2];
        aqw = qv.x; aqx = qv.y; aqy = qv.z; aqz = qv.w;
    }
    float xw0, xw1, xw2;
    {
        float Rf[9];
        quat_to_R(aqw, aqx, aqy, aqz, Rf);
        xw0 = Rf[0] * gx + Rf[1] * gy + Rf[2] * gz + apx;
        xw1 = Rf[3] * gx + Rf[4] * gy + Rf[5] * gz + apy;
        xw2 = Rf[6] * gx + Rf[7] * gy + Rf[8] * gz + apz;
    }

    float wsum = 0.f, mu0 = 0.f, mu1 = 0.f, mu2 = 0.f;
    float qb0 = 0.f, qb1 = 0.f, qb2 = 0.f, qb3 = 0.f;
    float wk[4];

#pragma unroll
    for (int k = 0; k < KNN / LPG; k++) {
        const int j = js[k];

        float prx, pry, prz, rw, rx, ry, rz;
        float plx, ply, plz, lw, lx, ly, lz;
        float sg;
        if (PACKED) {
            const float4* pkr = reinterpret_cast<const float4*>(packed + (base_rt + (size_t)j) * 8);
            float4 xr = pkr[0], qr = pkr[1];
            prx = xr.x; pry = xr.y; prz = xr.z; sg = xr.w;
            rw = qr.x; rx = qr.y; ry = qr.z; rz = qr.w;
            const float4* pkl = reinterpret_cast<const float4*>(packed + (base_t + (size_t)j) * 8);
            float4 xl = pkl[0], ql = pkl[1];
            plx = xl.x; ply = xl.y; plz = xl.z;
            lw = ql.x; lx = ql.y; ly = ql.z; lz = ql.w;
        } else {
            const float* pr = node_xyz + (base_rt + (size_t)j) * 3;
            prx = pr[0]; pry = pr[1]; prz = pr[2];
            const float4 qr = *reinterpret_cast<const float4*>(node_quat + (base_rt + (size_t)j) * 4);
            rw = qr.x; rx = qr.y; ry = qr.z; rz = qr.w;
            const float* pl = node_xyz + (base_t + (size_t)j) * 3;
            plx = pl[0]; ply = pl[1]; plz = pl[2];
            const float4 ql = *reinterpret_cast<const float4*>(node_quat + (base_t + (size_t)j) * 4);
            lw = ql.x; lx = ql.y; ly = ql.z; lz = ql.w;
            sg = node_sigma[j];
        }

        const float dx = xw0 - prx;
        const float dy = xw1 - pry;
        const float dz = xw2 - prz;
        const float dsq = dx * dx + dy * dy + dz * dz;

        const float w = __expf(-dsq / (2.f * sg * sg + 1e-8f));
        wk[k] = w;

        if (!PACKED) {
            // packed path stores normalized quats; raw path normalizes here
            float inv = rsqrtf(fmaxf(rw * rw + rx * rx + ry * ry + rz * rz, 1e-24f));
            rw *= inv; rx *= inv; ry *= inv; rz *= inv;
            inv = rsqrtf(fmaxf(lw * lw + lx * lx + ly * ly + lz * lz, 1e-24f));
            lw *= inv; lx *= inv; ly *= inv; lz *= inv;
        }
        // q_rel = q_live * conj(q_ref)
        const float qw =  lw * rw + lx * rx + ly * ry + lz * rz;
        const float qx = -lw * rx + lx * rw - ly * rz + lz * ry;
        const float qy = -lw * ry + lx * rz + ly * rw - lz * rx;
        const float qz = -lw * rz - lx * ry + ly * rx + lz * rw;

        float Rr[9];
        quat_to_R(qw, qx, qy, qz, Rr);

        const float m0 = Rr[0] * dx + Rr[1] * dy + Rr[2] * dz + plx;
        const float m1 = Rr[3] * dx + Rr[4] * dy + Rr[5] * dz + ply;
        const float m2 = Rr[6] * dx + Rr[7] * dy + Rr[8] * dz + plz;

        wsum += w;
        mu0 += w * m0; mu1 += w * m1; mu2 += w * m2;
        qb0 += w * qw; qb1 += w * qx; qb2 += w * qy; qb3 += w * qz;
    }

#pragma unroll
    for (int m = 1; m < LPG; m <<= 1) {
        wsum += __shfl_xor(wsum, m);
        mu0  += __shfl_xor(mu0, m);  mu1 += __shfl_xor(mu1, m);  mu2 += __shfl_xor(mu2, m);
        qb0  += __shfl_xor(qb0, m);  qb1 += __shfl_xor(qb1, m);
        qb2  += __shfl_xor(qb2, m);  qb3 += __shfl_xor(qb3, m);
    }

    const float invw = 1.f / (wsum + 1e-8f);
    const size_t Ns = (size_t)N, ns = (size_t)n;

    // --- sem: feature-sliced. Lane `sub` owns features [8*sub, 8*sub+8). ---
    float sm0 = 0.f, sm1 = 0.f, sm2 = 0.f, sm3 = 0.f;
    float sm4 = 0.f, sm5 = 0.f, sm6 = 0.f, sm7 = 0.f;
    const float4* sem4 = reinterpret_cast<const float4*>(node_sem);
#pragma unroll
    for (int kk = 0; kk < KNN; kk++) {
        const int src = kk >> 2;
        const int idx = kk & 3;
        const int   jk = __shfl(js[idx], src, LPG);
        const float wkk = __shfl(wk[idx], src, LPG);
        const float4 v0 = sem4[(size_t)jk * (FSEM / 4) + sub * 2 + 0];
        const float4 v1 = sem4[(size_t)jk * (FSEM / 4) + sub * 2 + 1];
        sm0 += wkk * v0.x; sm1 += wkk * v0.y; sm2 += wkk * v0.z; sm3 += wkk * v0.w;
        sm4 += wkk * v1.x; sm5 += wkk * v1.y; sm6 += wkk * v1.z; sm7 += wkk * v1.w;
    }

    if (sub == 0) {
        out[3 * ns + 0] = mu0 * invw;
        out[3 * ns + 1] = mu1 * invw;
        out[3 * ns + 2] = mu2 * invw;
    } else if (sub == 1) {
        // fr_live = q2R(qb*invw) @ (Rref @ q2R(gs_rot)); invw BEFORE q2R (fp32
        // subnormal guard). Rref recomputed from the live attach quat.
        float4 qg;
        if (SORTED) qg = rotA[g];
        else        qg = *reinterpret_cast<const float4*>(gs_rot + 4 * ns);
        float Rref[9];
        quat_to_R(aqw, aqx, aqy, aqz, Rref);
        float Rg[9];
        quat_to_R(qg.x, qg.y, qg.z, qg.w, Rg);
        float Rw[9];
#pragma unroll
        for (int i = 0; i < 3; i++)
#pragma unroll
            for (int j = 0; j < 3; j++)
                Rw[3 * i + j] = Rref[3 * i] * Rg[j] + Rref[3 * i + 1] * Rg[3 + j] + Rref[3 * i + 2] * Rg[6 + j];
        float Rb[9];
        quat_to_R(qb0 * invw, qb1 * invw, qb2 * invw, qb3 * invw, Rb);
        float* ofr = out + 3 * Ns + 9 * ns;
#pragma unroll
        for (int i = 0; i < 3; i++)
#pragma unroll
            for (int j = 0; j < 3; j++)
                ofr[3 * i + j] = Rb[3 * i] * Rw[j] + Rb[3 * i + 1] * Rw[3 + j] + Rb[3 * i + 2] * Rw[6 + j];
    }

    float4* osem = reinterpret_cast<float4*>(out + 28 * Ns + FSEM * ns);
    osem[sub * 2 + 0] = make_float4(sm0 * invw, sm1 * invw, sm2 * invw, sm3 * invw);
    osem[sub * 2 + 1] = make_float4(sm4 * invw, sm5 * invw, sm6 * invw, sm7 * invw);
}

extern "C" void kernel_launch(void* const* d_in, const int* in_sizes, int n_in,
                              void* d_out, int out_size, void* d_ws, size_t ws_size,
                              hipStream_t stream)
{
    const float* gs_xyz     = (const float*)d_in[0];
    const float* gs_rot     = (const float*)d_in[1];
    const float* gs_scal    = (const float*)d_in[2];
    const float* gs_opa     = (const float*)d_in[3];
    const float* feat_dc    = (const float*)d_in[4];
    const float* feat_rest  = (const float*)d_in[5];
    const float* node_xyz   = (const float*)d_in[6];
    const float* node_quat  = (const float*)d_in[7];
    const float* node_sigma = (const float*)d_in[8];
    const float* node_sem   = (const float*)d_in[9];
    const int* attach_ind   = (const int*)d_in[10];
    const int* ref_time     = (const int*)d_in[11];
    const int* topo_knn     = (const int*)d_in[12];
    const int* t_ptr        = (const int*)d_in[13];

    const int N = in_sizes[0] / 3;
    const int M = in_sizes[8];                 // node_sigma is (M,1)
    const int TM = in_sizes[6] / 3;            // T*M
    const int B  = TM;                         // exact sort buckets: key = rt*M + a
    const int nchunk = (B + CHUNK - 1) / CHUNK;

    float* out = (float*)d_out;

    const int block = 256;
    const int gridN = (N + block - 1) / block;
    const long long threads = (long long)N * LPG;
    const int gridM = (int)((threads + block - 1) / block);
    const int gridPH = (((TM > N ? TM : N)) + block - 1) / block;

    // workspace layout (floats): packed | metaA | rotA | cnt | blk
    const size_t f_packed = (size_t)TM * 8;
    const size_t f_meta   = (size_t)N * 8;
    const size_t f_rot    = (size_t)N * 4;
    const size_t i_cnt    = (size_t)B;
    const size_t i_blk    = (size_t)MAXCHUNK;
    const size_t need_sort   = (f_packed + f_meta + f_rot + i_cnt + i_blk) * sizeof(float);
    const size_t need_packed = f_packed * sizeof(float);

    if (ws_size >= need_sort && nchunk <= MAXCHUNK && (B & 3) == 0) {
        float*  packed = (float*)d_ws;
        float4* metaA  = (float4*)(packed + f_packed);
        float4* rotA   = (float4*)(packed + f_packed + f_meta);
        int*    cnt    = (int*)(packed + f_packed + f_meta + f_rot);
        int*    blk    = cnt + i_cnt;

        // one memset covers cnt + blk (contiguous)
        hipMemsetAsync(cnt, 0, (i_cnt + i_blk) * sizeof(int), stream);
        hipLaunchKernelGGL(k_pack_hist, dim3(gridPH), dim3(block), 0, stream,
                           node_xyz, node_quat, node_sigma, attach_ind, ref_time,
                           packed, cnt, TM, M, N);
        hipLaunchKernelGGL(k_scan1, dim3(nchunk), dim3(block), 0, stream, cnt, blk, B);
        hipLaunchKernelGGL(k_scatter_elem, dim3(gridN), dim3(block), 0, stream,
                           attach_ind, ref_time, gs_xyz, gs_rot, cnt, blk,
                           metaA, rotA, gs_scal, gs_opa, feat_dc, feat_rest,
                           out, N, M, nchunk);
        hipLaunchKernelGGL((dynscf_kernel<true, true>), dim3(gridM), dim3(block), 0, stream,
                           gs_xyz, gs_rot, node_xyz, node_quat, packed, node_sigma, node_sem,
                           attach_ind, ref_time, topo_knn, t_ptr, metaA, rotA, out, N, M);
    } else if (ws_size >= need_packed) {
        float* packed = (float*)d_ws;
        hipLaunchKernelGGL(k_pack_hist, dim3(gridPH), dim3(block), 0, stream,
                           node_xyz, node_quat, node_sigma, attach_ind, ref_time,
                           packed, (int*)nullptr, TM, M, 0);
        hipLaunchKernelGGL((dynscf_kernel<true, false>), dim3(gridM), dim3(block), 0, stream,
                           gs_xyz, gs_rot, node_xyz, node_quat, packed, node_sigma, node_sem,
                           attach_ind, ref_time, topo_knn, t_ptr,
                           (const float4*)nullptr, (const float4*)nullptr, out, N, M);
        hipLaunchKernelGGL(k_elem, dim3(gridN), dim3(block), 0, stream,
                           gs_scal, gs_opa, feat_dc, feat_rest, out, N);
    } else {
        hipLaunchKernelGGL((dynscf_kernel<false, false>), dim3(gridM), dim3(block), 0, stream,
                           gs_xyz, gs_rot, node_xyz, node_quat, (const float*)nullptr,
                           node_sigma, node_sem,
                           attach_ind, ref_time, topo_knn, t_ptr,
                           (const float4*)nullptr, (const float4*)nullptr, out, N, M);
        hipLaunchKernelGGL(k_elem, dim3(gridN), dim3(block), 0, stream,
                           gs_scal, gs_opa, feat_dc, feat_rest, out, N);
    }
}

// Round 11
// 207.758 us; speedup vs baseline: 1.5102x; 1.0072x over previous
//
#include <hip/hip_runtime.h>

#define KNN 16
#define FSEM 32
#define LPG 4                 // 4 lanes cooperate per gaussian
#define NXCD 8
#define CHUNK 1024            // scan1 buckets per block (B=400K -> 391 chunks)
#define MAXCHUNK 512          // scatter's in-LDS prefix capacity (>= nchunk)

__device__ __forceinline__ float sigmoidf_(float x) { return 1.0f / (1.0f + __expf(-x)); }

// q / clip(|q|,1e-12) -> row-major 3x3
__device__ __forceinline__ void quat_to_R(float qw, float qx, float qy, float qz, float* R) {
    float d = qw * qw + qx * qx + qy * qy + qz * qz;
    float inv = rsqrtf(fmaxf(d, 1e-24f));
    float w = qw * inv, x = qx * inv, y = qy * inv, z = qz * inv;
    R[0] = 1.f - 2.f * (y * y + z * z); R[1] = 2.f * (x * y - w * z); R[2] = 2.f * (x * z + w * y);
    R[3] = 2.f * (x * y + w * z); R[4] = 1.f - 2.f * (x * x + z * z); R[5] = 2.f * (y * z - w * x);
    R[6] = 2.f * (x * z - w * y); R[7] = 2.f * (y * z + w * x); R[8] = 1.f - 2.f * (x * x + y * y);
}

__device__ __forceinline__ void elem_outputs(int n, int N,
                                             const float* __restrict__ gs_scal,
                                             const float* __restrict__ gs_opa,
                                             const float* __restrict__ feat_dc,
                                             const float* __restrict__ feat_rest,
                                             float* __restrict__ out)
{
    const size_t Ns = (size_t)N, ns = (size_t)n;
    float* os = out + 12 * Ns + 3 * ns;
    os[0] = 0.1f * sigmoidf_(gs_scal[3 * ns + 0]);
    os[1] = 0.1f * sigmoidf_(gs_scal[3 * ns + 1]);
    os[2] = 0.1f * sigmoidf_(gs_scal[3 * ns + 2]);

    out[15 * Ns + ns] = sigmoidf_(gs_opa[ns]);

    float* osph = out + 16 * Ns + 12 * ns;   // 16B-aligned
    float4 v0 = make_float4(feat_dc[3 * ns + 0], feat_dc[3 * ns + 1], feat_dc[3 * ns + 2],
                            feat_rest[9 * ns + 0]);
    float4 v1 = make_float4(feat_rest[9 * ns + 1], feat_rest[9 * ns + 2],
                            feat_rest[9 * ns + 3], feat_rest[9 * ns + 4]);
    float4 v2 = make_float4(feat_rest[9 * ns + 5], feat_rest[9 * ns + 6],
                            feat_rest[9 * ns + 7], feat_rest[9 * ns + 8]);
    reinterpret_cast<float4*>(osph)[0] = v0;
    reinterpret_cast<float4*>(osph)[1] = v1;
    reinterpret_cast<float4*>(osph)[2] = v2;
}

// ---- tier-1 pack: FUSED 64B row per (rt,j): {ref_xyz,sigma, ref_quat(nrm),
// live_xyz,0, live_quat(nrm)}. One L2 line per neighbor in main (vs 2 for the
// split layout — R10 arithmetic: packed gathers are ~6.4M of ~10M L2 lines).
// Also exact-key histogram (key = rt*M + a). cnt pre-zeroed by memset. ----
__global__ void __launch_bounds__(256)
k_pack_fused_hist(const float* __restrict__ node_xyz, const float* __restrict__ node_quat,
                  const float* __restrict__ node_sigma,
                  const int* __restrict__ attach, const int* __restrict__ rtime,
                  const int* __restrict__ t_ptr,
                  float* __restrict__ fused, int* __restrict__ cnt,
                  int TM, int M, int N)
{
    const int p = blockIdx.x * blockDim.x + threadIdx.x;
    if (p < TM) {
        const int t = t_ptr[0];
        const int j = p - (p / M) * M;             // p % M
        const size_t pl = (size_t)t * (size_t)M + (size_t)j;

        const float* xr = node_xyz + 3 * (size_t)p;
        float4 qr = reinterpret_cast<const float4*>(node_quat)[p];
        float inv = rsqrtf(fmaxf(qr.x * qr.x + qr.y * qr.y + qr.z * qr.z + qr.w * qr.w, 1e-24f));
        qr.x *= inv; qr.y *= inv; qr.z *= inv; qr.w *= inv;

        const float* xl = node_xyz + 3 * pl;
        float4 ql = reinterpret_cast<const float4*>(node_quat)[pl];
        inv = rsqrtf(fmaxf(ql.x * ql.x + ql.y * ql.y + ql.z * ql.z + ql.w * ql.w, 1e-24f));
        ql.x *= inv; ql.y *= inv; ql.z *= inv; ql.w *= inv;

        float4* dst = reinterpret_cast<float4*>(fused + 16 * (size_t)p);
        dst[0] = make_float4(xr[0], xr[1], xr[2], node_sigma[j]);
        dst[1] = qr;
        dst[2] = make_float4(xl[0], xl[1], xl[2], 0.f);
        dst[3] = ql;
    }
    if (cnt && p < N) {
        atomicAdd(&cnt[rtime[p] * M + attach[p]], 1);
    }
}

// ---- tier-2 pack: 32B split row (R10-proven) ----
__global__ void __launch_bounds__(256)
k_pack_hist(const float* __restrict__ node_xyz, const float* __restrict__ node_quat,
            const float* __restrict__ node_sigma,
            const int* __restrict__ attach, const int* __restrict__ rtime,
            float* __restrict__ packed, int* __restrict__ cnt,
            int TM, int M, int N)
{
    const int p = blockIdx.x * blockDim.x + threadIdx.x;
    if (p < TM) {
        const int node = p - (p / M) * M;          // p % M
        const float* x = node_xyz + 3 * (size_t)p;
        float4 q = reinterpret_cast<const float4*>(node_quat)[p];
        const float inv = rsqrtf(fmaxf(q.x * q.x + q.y * q.y + q.z * q.z + q.w * q.w, 1e-24f));
        q.x *= inv; q.y *= inv; q.z *= inv; q.w *= inv;
        float4 a = make_float4(x[0], x[1], x[2], node_sigma[node]);
        float4* dst = reinterpret_cast<float4*>(packed + 8 * (size_t)p);
        dst[0] = a;
        dst[1] = q;
    }
    if (cnt && p < N) {
        atomicAdd(&cnt[rtime[p] * M + attach[p]], 1);
    }
}

// ---- scan1: per-block exclusive scan over CHUNK=1024 buckets (int4/thread),
// chunk total -> blk[c]. No device fences (R9: fence/block = 110us). ----
__global__ void __launch_bounds__(256)
k_scan1(int* __restrict__ cnt, int* __restrict__ blk, int B)
{
    __shared__ int sh[256];
    const int base = blockIdx.x * CHUNK + threadIdx.x * 4;
    int4 v = make_int4(0, 0, 0, 0);
    if (base + 3 < B) v = *reinterpret_cast<const int4*>(&cnt[base]);   // B%4==0
    const int s = v.x + v.y + v.z + v.w;

    sh[threadIdx.x] = s;
    __syncthreads();
    int acc = s;
#pragma unroll
    for (int off = 1; off < 256; off <<= 1) {
        int u = (threadIdx.x >= off) ? sh[threadIdx.x - off] : 0;
        __syncthreads();
        acc += u;
        sh[threadIdx.x] = acc;
        __syncthreads();
    }
    const int excl = acc - s;

    if (base + 3 < B) {
        int4 w;
        w.x = excl;
        w.y = excl + v.x;
        w.z = excl + v.x + v.y;
        w.w = excl + v.x + v.y + v.z;
        *reinterpret_cast<int4*>(&cnt[base]) = w;    // exclusive within chunk
    }
    if (threadIdx.x == 255) blk[blockIdx.x] = acc;   // chunk total
}

// ---- scatter + elem fused; in-block chunk-total prefix (R10-proven). ----
__global__ void __launch_bounds__(256)
k_scatter_elem(const int* __restrict__ attach, const int* __restrict__ rtime,
               const float* __restrict__ gs_xyz,
               const float* __restrict__ gs_rot,
               int* __restrict__ cnt, const int* __restrict__ blk,
               float4* __restrict__ metaA, float4* __restrict__ rotA,
               const float* __restrict__ gs_scal,
               const float* __restrict__ gs_opa,
               const float* __restrict__ feat_dc,
               const float* __restrict__ feat_rest,
               float* __restrict__ out,
               int N, int M, int nchunk)
{
    __shared__ int raw[MAXCHUNK];
    __shared__ int ps[256];

    {
        const int i0 = threadIdx.x, i1 = threadIdx.x + 256;
        raw[i0] = (i0 < nchunk) ? blk[i0] : 0;
        raw[i1] = (i1 < nchunk) ? blk[i1] : 0;
    }
    __syncthreads();
    {
        const int pairsum = raw[2 * threadIdx.x] + raw[2 * threadIdx.x + 1];
        ps[threadIdx.x] = pairsum;
        __syncthreads();
        int acc = pairsum;
#pragma unroll
        for (int off = 1; off < 256; off <<= 1) {
            int u = (threadIdx.x >= off) ? ps[threadIdx.x - off] : 0;
            __syncthreads();
            acc += u;
            ps[threadIdx.x] = acc;
            __syncthreads();
        }
        const int excl = acc - pairsum;
        __syncthreads();
        ps[threadIdx.x] = excl;
    }
    __syncthreads();

    const int n = blockIdx.x * blockDim.x + threadIdx.x;
    if (n >= N) return;
    const int a = attach[n], rt = rtime[n];
    const int key = rt * M + a;
    const int c = key / CHUNK;
    const int cpref = ps[c >> 1] + ((c & 1) ? raw[c & ~1] : 0);
    const int pos = cpref + atomicAdd(&cnt[key], 1);

    metaA[2 * (size_t)pos]     = make_float4(__int_as_float(n), __int_as_float(a),
                                             __int_as_float(rt), 0.f);
    metaA[2 * (size_t)pos + 1] = make_float4(gs_xyz[3 * (size_t)n + 0],
                                             gs_xyz[3 * (size_t)n + 1],
                                             gs_xyz[3 * (size_t)n + 2], 0.f);
    rotA[pos] = reinterpret_cast<const float4*>(gs_rot)[n];

    elem_outputs(n, N, gs_scal, gs_opa, feat_dc, feat_rest, out);
}

// ---- plain elementwise kernel (fallback tiers only) ----
__global__ void __launch_bounds__(256)
k_elem(const float* __restrict__ gs_scal,
       const float* __restrict__ gs_opa,
       const float* __restrict__ feat_dc,
       const float* __restrict__ feat_rest,
       float* __restrict__ out, int N)
{
    const int n = blockIdx.x * blockDim.x + threadIdx.x;
    if (n >= N) return;
    elem_outputs(n, N, gs_scal, gs_opa, feat_dc, feat_rest, out);
}

// ---- main skinning kernel ----
// FUSED: 64B row per (rt,j) holds ref+live -> 1 L2 line per neighbor.
// PACKED (tier-2): R10's split 32B rows. Raw: normalize in-loop.
template<bool FUSED, bool PACKED, bool SORTED>
__global__ void __launch_bounds__(256)
dynscf_kernel(const float* __restrict__ gs_xyz,
              const float* __restrict__ gs_rot,
              const float* __restrict__ node_xyz,
              const float* __restrict__ node_quat,
              const float* __restrict__ packed,   // split rows (tier-2) or fused rows (tier-1)
              const float* __restrict__ node_sigma,
              const float* __restrict__ node_sem,
              const int* __restrict__ attach_ind,
              const int* __restrict__ ref_time,
              const int* __restrict__ topo_knn,
              const int* __restrict__ t_ptr,
              const float4* __restrict__ metaA,
              const float4* __restrict__ rotA,
              float* __restrict__ out,
              int N, int M)
{
    int bid = blockIdx.x;
    if (SORTED) {
        // m204 bijective chunked XCD swizzle: contiguous sorted range per XCD.
        const int nwg = gridDim.x;
        const int q = nwg / NXCD, r = nwg % NXCD;
        const int xcd = bid % NXCD, idx = bid / NXCD;
        bid = (xcd < r ? xcd * (q + 1) : r * (q + 1) + (xcd - r) * q) + idx;
    }
    const int tid = bid * blockDim.x + threadIdx.x;
    const int g   = tid >> 2;            // sorted-order group index
    const int sub = tid & (LPG - 1);
    if (g >= N) return;

    const int t = t_ptr[0];

    int n, a, rt;
    float gx, gy, gz;
    if (SORTED) {
        const float4 m0 = metaA[2 * (size_t)g];
        const float4 m1 = metaA[2 * (size_t)g + 1];
        n  = __float_as_int(m0.x);
        a  = __float_as_int(m0.y);
        rt = __float_as_int(m0.z);
        gx = m1.x; gy = m1.y; gz = m1.z;
    } else {
        n  = g;
        a  = attach_ind[n];
        rt = ref_time[n];
        gx = gs_xyz[3 * (size_t)n + 0];
        gy = gs_xyz[3 * (size_t)n + 1];
        gz = gs_xyz[3 * (size_t)n + 2];
    }

    const size_t base_rt = (size_t)rt * (size_t)M;
    const size_t base_t  = (size_t)t  * (size_t)M;

    const int4 kv = reinterpret_cast<const int4*>(topo_knn)[(size_t)a * (KNN / 4) + sub];
    const int js[4] = { kv.x, kv.y, kv.z, kv.w };

    // --- attach node @ ref time ---
    float apx, apy, apz, aqw, aqx, aqy, aqz;
    if (FUSED) {
        const float4* pk = reinterpret_cast<const float4*>(packed + (base_rt + (size_t)a) * 16);
        float4 xz = pk[0], qv = pk[1];
        apx = xz.x; apy = xz.y; apz = xz.z;
        aqw = qv.x; aqx = qv.y; aqy = qv.z; aqz = qv.w;
    } else if (PACKED) {
        const float4* pk = reinterpret_cast<const float4*>(packed + (base_rt + (size_t)a) * 8);
        float4 xz = pk[0], qv = pk[1];
        apx = xz.x; apy = xz.y; apz = xz.z;
        aqw = qv.x; aqx = qv.y; aqy = qv.z; aqz = qv.w;
    } else {
        const float4 qv = *reinterpret_cast<const float4*>(node_quat + (base_rt + (size_t)a) * 4);
        const float* pa = node_xyz + (base_rt + (size_t)a) * 3;
        apx = pa[0]; apy = pa[1]; apz = pa[2];
        aqw = qv.x; aqx = qv.y; aqy = qv.z; aqz = qv.w;
    }
    float xw0, xw1, xw2;
    {
        float Rf[9];
        quat_to_R(aqw, aqx, aqy, aqz, Rf);
        xw0 = Rf[0] * gx + Rf[1] * gy + Rf[2] * gz + apx;
        xw1 = Rf[3] * gx + Rf[4] * gy + Rf[5] * gz + apy;
        xw2 = Rf[6] * gx + Rf[7] * gy + Rf[8] * gz + apz;
    }

    float wsum = 0.f, mu0 = 0.f, mu1 = 0.f, mu2 = 0.f;
    float qb0 = 0.f, qb1 = 0.f, qb2 = 0.f, qb3 = 0.f;
    float wk[4];

#pragma unroll
    for (int k = 0; k < KNN / LPG; k++) {
        const int j = js[k];

        float prx, pry, prz, rw, rx, ry, rz;
        float plx, ply, plz, lw, lx, ly, lz;
        float sg;
        if (FUSED) {
            // ONE 64B line: ref_xyz|sigma, ref_quat, live_xyz|0, live_quat
            const float4* fr_ = reinterpret_cast<const float4*>(packed + (base_rt + (size_t)j) * 16);
            float4 xr = fr_[0], qr = fr_[1], xl = fr_[2], ql = fr_[3];
            prx = xr.x; pry = xr.y; prz = xr.z; sg = xr.w;
            rw = qr.x; rx = qr.y; ry = qr.z; rz = qr.w;
            plx = xl.x; ply = xl.y; plz = xl.z;
            lw = ql.x; lx = ql.y; ly = ql.z; lz = ql.w;
        } else if (PACKED) {
            const float4* pkr = reinterpret_cast<const float4*>(packed + (base_rt + (size_t)j) * 8);
            float4 xr = pkr[0], qr = pkr[1];
            prx = xr.x; pry = xr.y; prz = xr.z; sg = xr.w;
            rw = qr.x; rx = qr.y; ry = qr.z; rz = qr.w;
            const float4* pkl = reinterpret_cast<const float4*>(packed + (base_t + (size_t)j) * 8);
            float4 xl = pkl[0], ql = pkl[1];
            plx = xl.x; ply = xl.y; plz = xl.z;
            lw = ql.x; lx = ql.y; ly = ql.z; lz = ql.w;
        } else {
            const float* pr = node_xyz + (base_rt + (size_t)j) * 3;
            prx = pr[0]; pry = pr[1]; prz = pr[2];
            const float4 qr = *reinterpret_cast<const float4*>(node_quat + (base_rt + (size_t)j) * 4);
            rw = qr.x; rx = qr.y; ry = qr.z; rz = qr.w;
            const float* pl = node_xyz + (base_t + (size_t)j) * 3;
            plx = pl[0]; ply = pl[1]; plz = pl[2];
            const float4 ql = *reinterpret_cast<const float4*>(node_quat + (base_t + (size_t)j) * 4);
            lw = ql.x; lx = ql.y; ly = ql.z; lz = ql.w;
            sg = node_sigma[j];
        }

        const float dx = xw0 - prx;
        const float dy = xw1 - pry;
        const float dz = xw2 - prz;
        const float dsq = dx * dx + dy * dy + dz * dz;

        const float w = __expf(-dsq / (2.f * sg * sg + 1e-8f));
        wk[k] = w;

        if (!FUSED && !PACKED) {
            // fused/packed rows store pre-normalized quats
            float inv = rsqrtf(fmaxf(rw * rw + rx * rx + ry * ry + rz * rz, 1e-24f));
            rw *= inv; rx *= inv; ry *= inv; rz *= inv;
            inv = rsqrtf(fmaxf(lw * lw + lx * lx + ly * ly + lz * lz, 1e-24f));
            lw *= inv; lx *= inv; ly *= inv; lz *= inv;
        }
        // q_rel = q_live * conj(q_ref)
        const float qw =  lw * rw + lx * rx + ly * ry + lz * rz;
        const float qx = -lw * rx + lx * rw - ly * rz + lz * ry;
        const float qy = -lw * ry + lx * rz + ly * rw - lz * rx;
        const float qz = -lw * rz - lx * ry + ly * rx + lz * rw;

        float Rr[9];
        quat_to_R(qw, qx, qy, qz, Rr);

        const float m0 = Rr[0] * dx + Rr[1] * dy + Rr[2] * dz + plx;
        const float m1 = Rr[3] * dx + Rr[4] * dy + Rr[5] * dz + ply;
        const float m2 = Rr[6] * dx + Rr[7] * dy + Rr[8] * dz + plz;

        wsum += w;
        mu0 += w * m0; mu1 += w * m1; mu2 += w * m2;
        qb0 += w * qw; qb1 += w * qx; qb2 += w * qy; qb3 += w * qz;
    }

#pragma unroll
    for (int m = 1; m < LPG; m <<= 1) {
        wsum += __shfl_xor(wsum, m);
        mu0  += __shfl_xor(mu0, m);  mu1 += __shfl_xor(mu1, m);  mu2 += __shfl_xor(mu2, m);
        qb0  += __shfl_xor(qb0, m);  qb1 += __shfl_xor(qb1, m);
        qb2  += __shfl_xor(qb2, m);  qb3 += __shfl_xor(qb3, m);
    }

    const float invw = 1.f / (wsum + 1e-8f);
    const size_t Ns = (size_t)N, ns = (size_t)n;

    // --- sem: feature-sliced. Lane `sub` owns features [8*sub, 8*sub+8). ---
    float sm0 = 0.f, sm1 = 0.f, sm2 = 0.f, sm3 = 0.f;
    float sm4 = 0.f, sm5 = 0.f, sm6 = 0.f, sm7 = 0.f;
    const float4* sem4 = reinterpret_cast<const float4*>(node_sem);
#pragma unroll
    for (int kk = 0; kk < KNN; kk++) {
        const int src = kk >> 2;
        const int idx = kk & 3;
        const int   jk = __shfl(js[idx], src, LPG);
        const float wkk = __shfl(wk[idx], src, LPG);
        const float4 v0 = sem4[(size_t)jk * (FSEM / 4) + sub * 2 + 0];
        const float4 v1 = sem4[(size_t)jk * (FSEM / 4) + sub * 2 + 1];
        sm0 += wkk * v0.x; sm1 += wkk * v0.y; sm2 += wkk * v0.z; sm3 += wkk * v0.w;
        sm4 += wkk * v1.x; sm5 += wkk * v1.y; sm6 += wkk * v1.z; sm7 += wkk * v1.w;
    }

    if (sub == 0) {
        out[3 * ns + 0] = mu0 * invw;
        out[3 * ns + 1] = mu1 * invw;
        out[3 * ns + 2] = mu2 * invw;
    } else if (sub == 1) {
        // fr_live = q2R(qb*invw) @ (Rref @ q2R(gs_rot)); invw BEFORE q2R (fp32
        // subnormal guard). Rref recomputed from the live attach quat.
        float4 qg;
        if (SORTED) qg = rotA[g];
        else        qg = *reinterpret_cast<const float4*>(gs_rot + 4 * ns);
        float Rref[9];
        quat_to_R(aqw, aqx, aqy, aqz, Rref);
        float Rg[9];
        quat_to_R(qg.x, qg.y, qg.z, qg.w, Rg);
        float Rw[9];
#pragma unroll
        for (int i = 0; i < 3; i++)
#pragma unroll
            for (int j = 0; j < 3; j++)
                Rw[3 * i + j] = Rref[3 * i] * Rg[j] + Rref[3 * i + 1] * Rg[3 + j] + Rref[3 * i + 2] * Rg[6 + j];
        float Rb[9];
        quat_to_R(qb0 * invw, qb1 * invw, qb2 * invw, qb3 * invw, Rb);
        float* ofr = out + 3 * Ns + 9 * ns;
#pragma unroll
        for (int i = 0; i < 3; i++)
#pragma unroll
            for (int j = 0; j < 3; j++)
                ofr[3 * i + j] = Rb[3 * i] * Rw[j] + Rb[3 * i + 1] * Rw[3 + j] + Rb[3 * i + 2] * Rw[6 + j];
    }

    float4* osem = reinterpret_cast<float4*>(out + 28 * Ns + FSEM * ns);
    osem[sub * 2 + 0] = make_float4(sm0 * invw, sm1 * invw, sm2 * invw, sm3 * invw);
    osem[sub * 2 + 1] = make_float4(sm4 * invw, sm5 * invw, sm6 * invw, sm7 * invw);
}

extern "C" void kernel_launch(void* const* d_in, const int* in_sizes, int n_in,
                              void* d_out, int out_size, void* d_ws, size_t ws_size,
                              hipStream_t stream)
{
    const float* gs_xyz     = (const float*)d_in[0];
    const float* gs_rot     = (const float*)d_in[1];
    const float* gs_scal    = (const float*)d_in[2];
    const float* gs_opa     = (const float*)d_in[3];
    const float* feat_dc    = (const float*)d_in[4];
    const float* feat_rest  = (const float*)d_in[5];
    const float* node_xyz   = (const float*)d_in[6];
    const float* node_quat  = (const float*)d_in[7];
    const float* node_sigma = (const float*)d_in[8];
    const float* node_sem   = (const float*)d_in[9];
    const int* attach_ind   = (const int*)d_in[10];
    const int* ref_time     = (const int*)d_in[11];
    const int* topo_knn     = (const int*)d_in[12];
    const int* t_ptr        = (const int*)d_in[13];

    const int N = in_sizes[0] / 3;
    const int M = in_sizes[8];                 // node_sigma is (M,1)
    const int TM = in_sizes[6] / 3;            // T*M
    const int B  = TM;                         // exact sort buckets: key = rt*M + a
    const int nchunk = (B + CHUNK - 1) / CHUNK;

    float* out = (float*)d_out;

    const int block = 256;
    const int gridN = (N + block - 1) / block;
    const long long threads = (long long)N * LPG;
    const int gridM = (int)((threads + block - 1) / block);
    const int gridPH = (((TM > N ? TM : N)) + block - 1) / block;

    // workspace tiers (floats):
    //   tier-1: fused(16/row) | metaA | rotA | cnt | blk   (~37 MB)
    //   tier-2: packed(8/row) | metaA | rotA | cnt | blk   (~24 MB, R10-proven)
    const size_t f_fused  = (size_t)TM * 16;
    const size_t f_packed = (size_t)TM * 8;
    const size_t f_meta   = (size_t)N * 8;
    const size_t f_rot    = (size_t)N * 4;
    const size_t i_cnt    = (size_t)B;
    const size_t i_blk    = (size_t)MAXCHUNK;
    const size_t need_fused  = (f_fused  + f_meta + f_rot + i_cnt + i_blk) * sizeof(float);
    const size_t need_sort   = (f_packed + f_meta + f_rot + i_cnt + i_blk) * sizeof(float);
    const size_t need_packed = f_packed * sizeof(float);

    const bool sortable = (nchunk <= MAXCHUNK) && ((B & 3) == 0);

    if (ws_size >= need_fused && sortable) {
        float*  fused  = (float*)d_ws;
        float4* metaA  = (float4*)(fused + f_fused);
        float4* rotA   = (float4*)(fused + f_fused + f_meta);
        int*    cnt    = (int*)(fused + f_fused + f_meta + f_rot);
        int*    blk    = cnt + i_cnt;

        hipMemsetAsync(cnt, 0, (i_cnt + i_blk) * sizeof(int), stream);
        hipLaunchKernelGGL(k_pack_fused_hist, dim3(gridPH), dim3(block), 0, stream,
                           node_xyz, node_quat, node_sigma, attach_ind, ref_time,
                           t_ptr, fused, cnt, TM, M, N);
        hipLaunchKernelGGL(k_scan1, dim3(nchunk), dim3(block), 0, stream, cnt, blk, B);
        hipLaunchKernelGGL(k_scatter_elem, dim3(gridN), dim3(block), 0, stream,
                           attach_ind, ref_time, gs_xyz, gs_rot, cnt, blk,
                           metaA, rotA, gs_scal, gs_opa, feat_dc, feat_rest,
                           out, N, M, nchunk);
        hipLaunchKernelGGL((dynscf_kernel<true, true, true>), dim3(gridM), dim3(block), 0, stream,
                           gs_xyz, gs_rot, node_xyz, node_quat, fused, node_sigma, node_sem,
                           attach_ind, ref_time, topo_knn, t_ptr, metaA, rotA, out, N, M);
    } else if (ws_size >= need_sort && sortable) {
        float*  packed = (float*)d_ws;
        float4* metaA  = (float4*)(packed + f_packed);
        float4* rotA   = (float4*)(packed + f_packed + f_meta);
        int*    cnt    = (int*)(packed + f_packed + f_meta + f_rot);
        int*    blk    = cnt + i_cnt;

        hipMemsetAsync(cnt, 0, (i_cnt + i_blk) * sizeof(int), stream);
        hipLaunchKernelGGL(k_pack_hist, dim3(gridPH), dim3(block), 0, stream,
                           node_xyz, node_quat, node_sigma, attach_ind, ref_time,
                           packed, cnt, TM, M, N);
        hipLaunchKernelGGL(k_scan1, dim3(nchunk), dim3(block), 0, stream, cnt, blk, B);
        hipLaunchKernelGGL(k_scatter_elem, dim3(gridN), dim3(block), 0, stream,
                           attach_ind, ref_time, gs_xyz, gs_rot, cnt, blk,
                           metaA, rotA, gs_scal, gs_opa, feat_dc, feat_rest,
                           out, N, M, nchunk);
        hipLaunchKernelGGL((dynscf_kernel<false, true, true>), dim3(gridM), dim3(block), 0, stream,
                           gs_xyz, gs_rot, node_xyz, node_quat, packed, node_sigma, node_sem,
                           attach_ind, ref_time, topo_knn, t_ptr, metaA, rotA, out, N, M);
    } else if (ws_size >= need_packed) {
        float* packed = (float*)d_ws;
        hipLaunchKernelGGL(k_pack_hist, dim3(gridPH), dim3(block), 0, stream,
                           node_xyz, node_quat, node_sigma, attach_ind, ref_time,
                           packed, (int*)nullptr, TM, M, 0);
        hipLaunchKernelGGL((dynscf_kernel<false, true, false>), dim3(gridM), dim3(block), 0, stream,
                           gs_xyz, gs_rot, node_xyz, node_quat, packed, node_sigma, node_sem,
                           attach_ind, ref_time, topo_knn, t_ptr,
                           (const float4*)nullptr, (const float4*)nullptr, out, N, M);
        hipLaunchKernelGGL(k_elem, dim3(gridN), dim3(block), 0, stream,
                           gs_scal, gs_opa, feat_dc, feat_rest, out, N);
    } else {
        hipLaunchKernelGGL((dynscf_kernel<false, false, false>), dim3(gridM), dim3(block), 0, stream,
                           gs_xyz, gs_rot, node_xyz, node_quat, (const float*)nullptr,
                           node_sigma, node_sem,
                           attach_ind, ref_time, topo_knn, t_ptr,
                           (const float4*)nullptr, (const float4*)nullptr, out, N, M);
        hipLaunchKernelGGL(k_elem, dim3(gridN), dim3(block), 0, stream,
                           gs_scal, gs_opa, feat_dc, feat_rest, out, N);
    }
}